// Round 9
// baseline (627.097 us; speedup 1.0000x reference)
//
#include <hip/hip_runtime.h>
#include <hip/hip_bf16.h>

#define NN 100000
#define NE 1600000
#define NF 128
#define NC 40
#define BN_EPS 1e-5f

#define NB 256          // bucket slots (power of 2); used: (NN+511)>>9 = 196
#define NBU ((NN + 511) >> 9)
#define PT_TILE 4096    // edges per partition tile
#define PT_GRID ((NE + PT_TILE - 1) / PT_TILE)  // 391
#define SBANK 256       // stat banks (6250 blocks -> chains ~24)
#define NTILES (NN / 16)   // 6250 row-tiles of 16, exact
#define LIN80_BLKS ((NTILES + 3) / 4)  // 1563, 4 single-tile waves/block

typedef __attribute__((ext_vector_type(8))) short short8;
typedef __attribute__((ext_vector_type(4))) float float4v;
typedef __attribute__((ext_vector_type(4))) int int4v;

__device__ __forceinline__ unsigned short f2b(float f) {
    __hip_bfloat16 h = __float2bfloat16(f);
    return *reinterpret_cast<unsigned short*>(&h);
}
__device__ __forceinline__ float b2f_hi(unsigned u) { return __uint_as_float(u & 0xffff0000u); }
__device__ __forceinline__ float b2f_lo(unsigned u) { return __uint_as_float(u << 16); }

// ---------------- CSR build: bucket-partitioned (single-writer regions) ----------------

__global__ __launch_bounds__(256) void bhist_kernel(const int* __restrict__ dst,
                                                    int* __restrict__ bhist) {
    __shared__ int lh[NB];
    int tid = threadIdx.x;
    lh[tid] = 0;
    __syncthreads();
    int base = blockIdx.x * PT_TILE;
    int cnt = min(PT_TILE, NE - base);
    const int4v* d4 = (const int4v*)(dst + base);
    int cnt4 = cnt >> 2;
    for (int i = tid; i < cnt4; i += 256) {
        int4v d = __builtin_nontemporal_load(d4 + i);
        atomicAdd(&lh[d[0] >> 9], 1);
        atomicAdd(&lh[d[1] >> 9], 1);
        atomicAdd(&lh[d[2] >> 9], 1);
        atomicAdd(&lh[d[3] >> 9], 1);
    }
    __syncthreads();
    if (lh[tid]) atomicAdd(&bhist[tid], lh[tid]);
}

__global__ __launch_bounds__(256) void bscan_kernel(const int* __restrict__ bhist,
                                                    int* __restrict__ bbase,
                                                    int* __restrict__ bcur) {
    __shared__ int lds[NB];
    int t = threadIdx.x;
    int v = bhist[t];
    lds[t] = v;
    __syncthreads();
    for (int off = 1; off < NB; off <<= 1) {
        int u = (t >= off) ? lds[t - off] : 0;
        __syncthreads();
        lds[t] += u;
        __syncthreads();
    }
    int ex = lds[t] - v;
    bbase[t] = ex;
    bcur[t] = ex;
}

__global__ __launch_bounds__(256) void part_kernel(const int* __restrict__ src,
                                                   const int* __restrict__ dst,
                                                   int* __restrict__ bcur,
                                                   int2* __restrict__ stage) {
    __shared__ int2 pairs[PT_TILE];  // 32 KB
    __shared__ int lhist[NB];
    __shared__ int gbase[NB];
    int tid = threadIdx.x;
    int base = blockIdx.x * PT_TILE;
    int cnt = min(PT_TILE, NE - base);
    int cnt4 = cnt >> 2;

    lhist[tid] = 0;
    __syncthreads();

    const int4v* d4 = (const int4v*)(dst + base);
    const int4v* s4 = (const int4v*)(src + base);
    for (int i = tid; i < cnt4; i += 256) {
        int4v d = __builtin_nontemporal_load(d4 + i);
        int4v s = __builtin_nontemporal_load(s4 + i);
#pragma unroll
        for (int j = 0; j < 4; ++j) {
            pairs[j * cnt4 + i] = make_int2(d[j], s[j]);
            atomicAdd(&lhist[d[j] >> 9], 1);
        }
    }
    __syncthreads();

    int c = lhist[tid];
    gbase[tid] = (c > 0) ? atomicAdd(&bcur[tid], c) : 0;
    lhist[tid] = 0;
    __syncthreads();

    for (int k = tid; k < cnt; k += 256) {
        int2 p = pairs[k];
        int b = p.x >> 9;
        int pos = atomicAdd(&lhist[b], 1);
        stage[gbase[b] + pos] = p;
    }
}

// Merged deg+scan+fill: one block per bucket (R7-verified).

__global__ __launch_bounds__(512) void bucket_build_kernel(const long long* __restrict__ stage,
                                                           const int* __restrict__ bbase,
                                                           const int* __restrict__ bcur,
                                                           int* __restrict__ row_ptr,
                                                           float* __restrict__ inv_cnt,
                                                           int* __restrict__ csr) {
    __shared__ int hist[512];
    __shared__ int sa[512], sb[512];  // scan ping-pong
    __shared__ int cur[512];
    int tid = threadIdx.x;
    int b = blockIdx.x;
    int s = bbase[b], e = bcur[b];

    hist[tid] = 0;
    __syncthreads();

    for (int i = s + tid; i < e; i += 512) {
        long long p = __builtin_nontemporal_load(stage + i);
        int dl = ((int)(p & 0xffffffffLL)) & 511;
        atomicAdd(&hist[dl], 1);
    }
    __syncthreads();

    sa[tid] = hist[tid];
    __syncthreads();
    int* pin = sa;
    int* pout = sb;
    for (int off = 1; off < 512; off <<= 1) {
        pout[tid] = pin[tid] + ((tid >= off) ? pin[tid - off] : 0);
        __syncthreads();
        int* t = pin; pin = pout; pout = t;
    }

    int d = hist[tid];
    int ex = pin[tid] - d;  // exclusive
    cur[tid] = ex;
    int n = b * 512 + tid;
    if (n < NN) {
        row_ptr[n] = s + ex;
        inv_cnt[n] = 1.0f / (float)(d > 0 ? d : 1);
    }
    if (b == 0 && tid == 0) row_ptr[NN] = NE;
    __syncthreads();

    for (int i = s + tid; i < e; i += 512) {
        long long p = __builtin_nontemporal_load(stage + i);
        int dl = ((int)(p & 0xffffffffLL)) & 511;
        int sv = (int)(p >> 32);
        int pos = atomicAdd(&cur[dl], 1);
        csr[s + pos] = sv;
    }
}

// ---------------- fp32 -> bf16 bulk convert ----------------

__global__ __launch_bounds__(256) void f2b4_kernel(const float* __restrict__ in,
                                                   unsigned short* __restrict__ out, int n4) {
    int i = blockIdx.x * 256 + threadIdx.x;
    if (i < n4) {
        float4 v = ((const float4*)in)[i];
        ushort4 o;
        o.x = f2b(v.x); o.y = f2b(v.y); o.z = f2b(v.z); o.w = f2b(v.w);
        ((ushort4*)out)[i] = o;
    }
}

// ---------------- pack W into MFMA fragment order ----------------

__global__ __launch_bounds__(64) void pack_w_kernel(const float* __restrict__ Wl,
                                                    const float* __restrict__ Wr,
                                                    unsigned short* __restrict__ Bp) {
    int nt = blockIdx.x & 7;
    int kk = blockIdx.x >> 3;
    int lane = threadIdx.x;
    int n = nt * 16 + (lane & 15);
    int kb = kk * 32 + (lane >> 4) * 8;
    size_t base = ((size_t)(kk * 8 + nt) * 64 + lane) * 8;
#pragma unroll
    for (int j = 0; j < 8; ++j) {
        int k = kb + j;
        float v = (k < NF) ? Wl[(size_t)n * NF + k] : Wr[(size_t)n * NF + (k - NF)];
        Bp[base + j] = f2b(v);
    }
}

__global__ __launch_bounds__(64) void pack_w80_kernel(const float* __restrict__ Wl,
                                                      const float* __restrict__ Wr,
                                                      unsigned short* __restrict__ Bp) {
    int nt = blockIdx.x % 5;
    int kk = blockIdx.x / 5;
    int lane = threadIdx.x;
    int n = nt * 16 + (lane & 15);
    int kb = kk * 32 + (lane >> 4) * 8;
    size_t base = ((size_t)(kk * 5 + nt) * 64 + lane) * 8;
#pragma unroll
    for (int j = 0; j < 8; ++j) {
        int k = kb + j;
        float v = (n < NC) ? Wl[(size_t)n * NF + k] : Wr[(size_t)(n - NC) * NF + k];
        Bp[base + j] = f2b(v);
    }
}

// ---------------- mean aggregation: quarter-wave per node ----------------

__global__ __launch_bounds__(256) void agg_mean_bf16(const unsigned short* __restrict__ X,
                                                     const int* __restrict__ csr,
                                                     const int* __restrict__ row_ptr,
                                                     const float* __restrict__ inv_cnt,
                                                     unsigned short* __restrict__ out) {
    int tid = threadIdx.x;
    int lane = tid & 63;
    int wave = tid >> 6;
    int qw = lane >> 4;
    int sl = lane & 15;
    int n = blockIdx.x * 16 + wave * 4 + qw;
    if (n >= NN) return;
    int s = row_ptr[n], e = row_ptr[n + 1];
    int foff = sl * 8;  // feature offset (8 bf16 = 16B per lane)

    float a[8];
#pragma unroll
    for (int j = 0; j < 8; ++j) a[j] = 0.f;

    int i = s;
    for (; i + 4 <= e; i += 4) {
        int s0 = csr[i], s1 = csr[i + 1], s2 = csr[i + 2], s3 = csr[i + 3];
        uint4 u0 = *(const uint4*)(X + (size_t)s0 * NF + foff);
        uint4 u1 = *(const uint4*)(X + (size_t)s1 * NF + foff);
        uint4 u2 = *(const uint4*)(X + (size_t)s2 * NF + foff);
        uint4 u3 = *(const uint4*)(X + (size_t)s3 * NF + foff);
        a[0] += b2f_lo(u0.x) + b2f_lo(u1.x) + b2f_lo(u2.x) + b2f_lo(u3.x);
        a[1] += b2f_hi(u0.x) + b2f_hi(u1.x) + b2f_hi(u2.x) + b2f_hi(u3.x);
        a[2] += b2f_lo(u0.y) + b2f_lo(u1.y) + b2f_lo(u2.y) + b2f_lo(u3.y);
        a[3] += b2f_hi(u0.y) + b2f_hi(u1.y) + b2f_hi(u2.y) + b2f_hi(u3.y);
        a[4] += b2f_lo(u0.z) + b2f_lo(u1.z) + b2f_lo(u2.z) + b2f_lo(u3.z);
        a[5] += b2f_hi(u0.z) + b2f_hi(u1.z) + b2f_hi(u2.z) + b2f_hi(u3.z);
        a[6] += b2f_lo(u0.w) + b2f_lo(u1.w) + b2f_lo(u2.w) + b2f_lo(u3.w);
        a[7] += b2f_hi(u0.w) + b2f_hi(u1.w) + b2f_hi(u2.w) + b2f_hi(u3.w);
    }
    for (; i < e; ++i) {
        uint4 u = *(const uint4*)(X + (size_t)csr[i] * NF + foff);
        a[0] += b2f_lo(u.x); a[1] += b2f_hi(u.x);
        a[2] += b2f_lo(u.y); a[3] += b2f_hi(u.y);
        a[4] += b2f_lo(u.z); a[5] += b2f_hi(u.z);
        a[6] += b2f_lo(u.w); a[7] += b2f_hi(u.w);
    }

    float ic = inv_cnt[n];
    uint4 o;
    o.x = (unsigned)f2b(a[0] * ic) | ((unsigned)f2b(a[1] * ic) << 16);
    o.y = (unsigned)f2b(a[2] * ic) | ((unsigned)f2b(a[3] * ic) << 16);
    o.z = (unsigned)f2b(a[4] * ic) | ((unsigned)f2b(a[5] * ic) << 16);
    o.w = (unsigned)f2b(a[6] * ic) | ((unsigned)f2b(a[7] * ic) << 16);
    *(uint4*)(out + (size_t)n * NF + foff) = o;
}

// ---------------- MFMA linear (128-out, K=256): ONE TILE PER BLOCK, straight-line ----------------
// R7 model (verified by fit): per-tile 24 loads sink to serial load;wait;mfma
// chains (~14.4K cyc/tile) because the tile LOOP lets the scheduler sink
// loop-invariant/per-tile loads to their uses, and grid 1250 caps block
// supply at ~3/CU. Fix both at once: one block = one tile, straight-line
// body (no loop -> nothing to sink into; all 24 loads cluster ahead of the
// MFMAs = 24-deep MLP per wave), grid 6250 = 24 blocks/CU of supply.
// Wave w computes nt {2w, 2w+1} (R3-verified mapping).

template <bool RELU, bool STATS>
__device__ __forceinline__ void lin_body(const unsigned short* __restrict__ Ab,
                                         const unsigned short* __restrict__ Xb,
                                         const unsigned short* __restrict__ Bp,
                                         const float* __restrict__ bias,
                                         unsigned short* __restrict__ outb,
                                         float* __restrict__ sums,
                                         float* ls) {
    int tid = threadIdx.x;
    int wave = tid >> 6;
    int lane = tid & 63;
    int quad = lane >> 4;
    int sl = lane & 15;
    const short8* Bv = (const short8*)Bp;

    if (STATS) {
        ls[tid] = 0.f;
        __syncthreads();
    }

    int rr = blockIdx.x * 16 + sl;  // node row this lane owns (6250*16 == NN, no tail)
    const unsigned short* arow = Ab + (size_t)rr * NF;
    const unsigned short* xrow = Xb + (size_t)rr * NF;

    // 16 B-fragment loads + 8 X-fragment loads + bias: all independent,
    // single basic block -> compiler clusters them ahead of the MFMAs.
    short8 bfr[8][2];
#pragma unroll
    for (int kk = 0; kk < 8; ++kk)
#pragma unroll
        for (int j = 0; j < 2; ++j)
            bfr[kk][j] = Bv[(kk * 8 + 2 * wave + j) * 64 + lane];

    short8 xf[8];
#pragma unroll
    for (int kk = 0; kk < 8; ++kk) {
        int kb = (kk & 3) * 32 + quad * 8;
        const unsigned short* asrc = (kk < 4) ? arow : xrow;
        xf[kk] = *(const short8*)(asrc + kb);
    }

    float4 bias4[2];
#pragma unroll
    for (int j = 0; j < 2; ++j)
        bias4[j] = *(const float4*)(bias + (2 * wave + j) * 16 + quad * 4);

    float4v acc[2];
#pragma unroll
    for (int j = 0; j < 2; ++j) acc[j] = (float4v){0.f, 0.f, 0.f, 0.f};

#pragma unroll
    for (int kk = 0; kk < 8; ++kk)
#pragma unroll
        for (int j = 0; j < 2; ++j)
            acc[j] = __builtin_amdgcn_mfma_f32_16x16x32_bf16(bfr[kk][j], xf[kk], acc[j], 0, 0, 0);

#pragma unroll
    for (int j = 0; j < 2; ++j) {
        int c0 = (2 * wave + j) * 16 + quad * 4;
        float v0 = acc[j][0] + bias4[j].x;
        float v1 = acc[j][1] + bias4[j].y;
        float v2 = acc[j][2] + bias4[j].z;
        float v3 = acc[j][3] + bias4[j].w;
        if (RELU) {
            v0 = fmaxf(v0, 0.f); v1 = fmaxf(v1, 0.f);
            v2 = fmaxf(v2, 0.f); v3 = fmaxf(v3, 0.f);
        }
        if (STATS) {
            atomicAdd(&ls[c0 + 0], v0); atomicAdd(&ls[128 + c0 + 0], v0 * v0);
            atomicAdd(&ls[c0 + 1], v1); atomicAdd(&ls[128 + c0 + 1], v1 * v1);
            atomicAdd(&ls[c0 + 2], v2); atomicAdd(&ls[128 + c0 + 2], v2 * v2);
            atomicAdd(&ls[c0 + 3], v3); atomicAdd(&ls[128 + c0 + 3], v3 * v3);
        }
        ushort4 o;
        o.x = f2b(v0); o.y = f2b(v1); o.z = f2b(v2); o.w = f2b(v3);
        *(ushort4*)(outb + (size_t)rr * NF + c0) = o;
    }

    if (STATS) {
        __syncthreads();
        atomicAdd(&sums[(blockIdx.x & (SBANK - 1)) * 256 + tid], ls[tid]);
    }
}

__global__ __launch_bounds__(256, 2) void lin_conv1_kernel(const unsigned short* __restrict__ Ab,
                                                           const unsigned short* __restrict__ Xb,
                                                           const unsigned short* __restrict__ Bp,
                                                           const float* __restrict__ bias,
                                                           unsigned short* __restrict__ outb) {
    lin_body<true, false>(Ab, Xb, Bp, bias, outb, nullptr, nullptr);
}

__global__ __launch_bounds__(256, 2) void lin_convx_kernel(const unsigned short* __restrict__ Ab,
                                                           const unsigned short* __restrict__ Xb,
                                                           const unsigned short* __restrict__ Bp,
                                                           const float* __restrict__ bias,
                                                           unsigned short* __restrict__ outb,
                                                           float* __restrict__ sums) {
    __shared__ float ls[256];
    lin_body<false, true>(Ab, Xb, Bp, bias, outb, sums, ls);
}

// ---------------- BN3 coefficients: fold banked sums, scale/shift per column ----------------

__global__ __launch_bounds__(128) void bn3_coef_kernel(const float* __restrict__ sums,
                                                       const float* __restrict__ g,
                                                       const float* __restrict__ be,
                                                       float* __restrict__ sc,
                                                       float* __restrict__ sh) {
    int c = threadIdx.x;
    float sv = 0.f, qv = 0.f;
    for (int b = 0; b < SBANK; ++b) {
        sv += sums[b * 256 + c];
        qv += sums[b * 256 + 128 + c];
    }
    float invN = 1.0f / (float)NN;
    float mu = sv * invN;
    float var = qv * invN - mu * mu;
    float s = rsqrtf(var + BN_EPS) * g[c];
    sc[c] = s;
    sh[c] = be[c] - mu * s;
}

// ---------------- MFMA linear conv2 (80-out, K=128): ONE TILE PER WAVE, straight-line ----------------
// Same single-tile treatment: 4 waves/block, each on its own tile; 40
// independent loads (20 B-frags + 16 coef + 4 X) cluster ahead of 20 MFMAs.
// Tail waves clamp to the last tile; duplicate writes are value-identical.

__global__ __launch_bounds__(256, 2) void lin80_mfma_kernel(const unsigned short* __restrict__ Xb,
                                                            const unsigned short* __restrict__ Bp,
                                                            const float* __restrict__ b2,
                                                            const float* __restrict__ bnsc,
                                                            const float* __restrict__ bnsh,
                                                            unsigned short* __restrict__ t40,
                                                            float* __restrict__ z40) {
    int tid = threadIdx.x;
    int wave = tid >> 6;
    int lane = tid & 63;
    int quad = lane >> 4;
    int sl = lane & 15;
    const short8* Bv = (const short8*)Bp;

    int t = blockIdx.x * 4 + wave;
    if (t >= NTILES) t = NTILES - 1;  // duplicate of last tile: benign identical writes
    int rr = t * 16 + sl;
    const unsigned short* xrow = Xb + (size_t)rr * NF;

    short8 bfr[4][5];
#pragma unroll
    for (int kk = 0; kk < 4; ++kk)
#pragma unroll
        for (int nt = 0; nt < 5; ++nt)
            bfr[kk][nt] = Bv[(kk * 5 + nt) * 64 + lane];

    float4 sc0[4], sc1[4], sh0[4], sh1[4];
#pragma unroll
    for (int kk = 0; kk < 4; ++kk) {
        int kb = kk * 32 + quad * 8;
        sc0[kk] = *(const float4*)(bnsc + kb);
        sc1[kk] = *(const float4*)(bnsc + kb + 4);
        sh0[kk] = *(const float4*)(bnsh + kb);
        sh1[kk] = *(const float4*)(bnsh + kb + 4);
    }

    uint4 u[4];
#pragma unroll
    for (int kk = 0; kk < 4; ++kk)
        u[kk] = *(const uint4*)(xrow + kk * 32 + quad * 8);

    float4v acc[5];
#pragma unroll
    for (int nt = 0; nt < 5; ++nt) acc[nt] = (float4v){0.f, 0.f, 0.f, 0.f};

#pragma unroll
    for (int kk = 0; kk < 4; ++kk) {
        short8 xf;
        xf[0] = (short)f2b(fmaxf(b2f_lo(u[kk].x) * sc0[kk].x + sh0[kk].x, 0.f));
        xf[1] = (short)f2b(fmaxf(b2f_hi(u[kk].x) * sc0[kk].y + sh0[kk].y, 0.f));
        xf[2] = (short)f2b(fmaxf(b2f_lo(u[kk].y) * sc0[kk].z + sh0[kk].z, 0.f));
        xf[3] = (short)f2b(fmaxf(b2f_hi(u[kk].y) * sc0[kk].w + sh0[kk].w, 0.f));
        xf[4] = (short)f2b(fmaxf(b2f_lo(u[kk].z) * sc1[kk].x + sh1[kk].x, 0.f));
        xf[5] = (short)f2b(fmaxf(b2f_hi(u[kk].z) * sc1[kk].y + sh1[kk].y, 0.f));
        xf[6] = (short)f2b(fmaxf(b2f_lo(u[kk].w) * sc1[kk].z + sh1[kk].z, 0.f));
        xf[7] = (short)f2b(fmaxf(b2f_hi(u[kk].w) * sc1[kk].w + sh1[kk].w, 0.f));
#pragma unroll
        for (int nt = 0; nt < 5; ++nt)
            acc[nt] = __builtin_amdgcn_mfma_f32_16x16x32_bf16(bfr[kk][nt], xf, acc[nt], 0, 0, 0);
    }

#pragma unroll
    for (int nt = 0; nt < 5; ++nt) {
        int c0 = nt * 16 + quad * 4;
        if (c0 < NC) {
            ushort4 o;
            o.x = f2b(acc[nt][0]); o.y = f2b(acc[nt][1]);
            o.z = f2b(acc[nt][2]); o.w = f2b(acc[nt][3]);
            *(ushort4*)(t40 + (size_t)rr * NC + c0) = o;
        } else {
            float4 bz = *(const float4*)(b2 + c0 - NC);
            float4 o;
            o.x = acc[nt][0] + bz.x; o.y = acc[nt][1] + bz.y;
            o.z = acc[nt][2] + bz.z; o.w = acc[nt][3] + bz.w;
            *(float4*)(z40 + (size_t)rr * NC + (c0 - NC)) = o;
        }
    }
}

// ---------------- conv2 aggregation: 3 nodes/wave (R7 form, NO barrier after gather) ----------------

__global__ __launch_bounds__(256) void agg40_add_bf16(const unsigned short* __restrict__ T,
                                                      const float* __restrict__ Z,
                                                      const int* __restrict__ csr,
                                                      const int* __restrict__ row_ptr,
                                                      const float* __restrict__ inv_cnt,
                                                      float* __restrict__ out) {
    int tid = threadIdx.x;
    int lane = tid & 63;
    int wave = tid >> 6;
    if (lane >= 60) return;
    int sub = lane / 20;
    int sl = lane % 20;
    int n = blockIdx.x * 12 + wave * 3 + sub;
    if (n >= NN) return;
    int s = row_ptr[n], e = row_ptr[n + 1];
    const unsigned short* Tf = T + sl * 2;
    float a0 = 0.f, a1 = 0.f;
    int i = s;
    for (; i + 4 <= e; i += 4) {
        int s0 = csr[i], s1 = csr[i + 1], s2 = csr[i + 2], s3 = csr[i + 3];
        unsigned u0 = *(const unsigned*)(Tf + (size_t)s0 * NC);
        unsigned u1 = *(const unsigned*)(Tf + (size_t)s1 * NC);
        unsigned u2 = *(const unsigned*)(Tf + (size_t)s2 * NC);
        unsigned u3 = *(const unsigned*)(Tf + (size_t)s3 * NC);
        a0 += b2f_lo(u0) + b2f_lo(u1) + b2f_lo(u2) + b2f_lo(u3);
        a1 += b2f_hi(u0) + b2f_hi(u1) + b2f_hi(u2) + b2f_hi(u3);
    }
    for (; i < e; ++i) {
        unsigned u = *(const unsigned*)(Tf + (size_t)csr[i] * NC);
        a0 += b2f_lo(u);
        a1 += b2f_hi(u);
    }
    float ic = inv_cnt[n];
    const float2 zv = *(const float2*)(Z + (size_t)n * NC + sl * 2);
    float2 o;
    o.x = a0 * ic + zv.x;
    o.y = a1 * ic + zv.y;
    *(float2*)(out + (size_t)n * NC + sl * 2) = o;
}

// ---------------- batch norm (final, NC) ----------------
#define BN_GRID 640  // 640*256 divisible by 10 (F=40)

template <int F>
__global__ __launch_bounds__(256) void bn_stats2_kernel(const float* __restrict__ X,
                                                        float* __restrict__ sums) {
    __shared__ float ls[2 * F];
    int tid = threadIdx.x;
    for (int i = tid; i < 2 * F; i += 256) ls[i] = 0.f;
    __syncthreads();

    const int total4 = NN * F / 4;
    const int stride = BN_GRID * 256;
    int i0 = blockIdx.x * 256 + tid;
    int c0 = (i0 * 4) % F;
    float s0 = 0.f, s1 = 0.f, s2 = 0.f, s3 = 0.f;
    float q0 = 0.f, q1 = 0.f, q2 = 0.f, q3 = 0.f;
    for (int i = i0; i < total4; i += stride) {
        float4 v = ((const float4*)X)[i];
        s0 += v.x; q0 += v.x * v.x;
        s1 += v.y; q1 += v.y * v.y;
        s2 += v.z; q2 += v.z * v.z;
        s3 += v.w; q3 += v.w * v.w;
    }
    atomicAdd(&ls[c0 + 0], s0); atomicAdd(&ls[F + c0 + 0], q0);
    atomicAdd(&ls[c0 + 1], s1); atomicAdd(&ls[F + c0 + 1], q1);
    atomicAdd(&ls[c0 + 2], s2); atomicAdd(&ls[F + c0 + 2], q2);
    atomicAdd(&ls[c0 + 3], s3); atomicAdd(&ls[F + c0 + 3], q3);
    __syncthreads();
    for (int i = tid; i < 2 * F; i += 256) atomicAdd(&sums[i], ls[i]);
}

template <bool RELU>
__global__ __launch_bounds__(256) void bn_apply_kernel(float* __restrict__ X,
                                                       const float* __restrict__ sums,
                                                       const float* __restrict__ g,
                                                       const float* __restrict__ be,
                                                       int F, float invN) {
    size_t idx = (size_t)blockIdx.x * blockDim.x + threadIdx.x;
    size_t total = (size_t)NN * F;
    if (idx >= total) return;
    int t = (int)(idx % F);
    float mu = sums[t] * invN;
    float var = sums[F + t] * invN - mu * mu;
    float scale = rsqrtf(var + BN_EPS) * g[t];
    float v = (X[idx] - mu) * scale + be[t];
    if (RELU) v = fmaxf(v, 0.f);
    X[idx] = v;
}

// ---------------- launch ----------------

extern "C" void kernel_launch(void* const* d_in, const int* in_sizes, int n_in,
                              void* d_out, int out_size, void* d_ws, size_t ws_size,
                              hipStream_t stream) {
    const float* x   = (const float*)d_in[0];
    const int*   ei  = (const int*)d_in[1];
    const int*   srcv = ei;
    const int*   dstv = ei + NE;
    const float* W1l = (const float*)d_in[2];
    const float* b1  = (const float*)d_in[3];
    const float* W1r = (const float*)d_in[4];
    const float* Wxl = (const float*)d_in[5];
    const float* bx  = (const float*)d_in[6];
    const float* Wxr = (const float*)d_in[7];
    const float* W2l = (const float*)d_in[8];
    const float* b2  = (const float*)d_in[9];
    const float* W2r = (const float*)d_in[10];
    const float* g3  = (const float*)d_in[11];
    const float* be3 = (const float*)d_in[12];
    const float* g2  = (const float*)d_in[13];
    const float* be2 = (const float*)d_in[14];
    float* out = (float*)d_out;

    // workspace carve (16B aligned)
    char* w = (char*)d_ws;
    unsigned short* xb   = (unsigned short*)w; w += (size_t)NN * NF * 2;   // 25.6 MB
    unsigned short* h1b  = (unsigned short*)w; w += (size_t)NN * NF * 2;   // 25.6 MB
    unsigned short* aggb = (unsigned short*)w; w += (size_t)NN * NF * 2;   // 25.6 MB
    unsigned short* h2b  = (unsigned short*)w; w += (size_t)NN * NF * 2;   // 25.6 MB
    int* csr     = (int*)w; w += (size_t)NE * 4;                           // 6.4 MB
    int* row_ptr = (int*)w; w += (size_t)(NN + 4) * 4;
    float* inv_cnt = (float*)w; w += (size_t)NN * 4;
    float* bnbuf3  = (float*)w; w += (size_t)SBANK * 256 * 4;              // 256 KB banked
    float* bnbuf2  = (float*)w; w += 2 * NC * 4;
    float* bnsc    = (float*)w; w += NF * 4;
    float* bnsh    = (float*)w; w += NF * 4;
    unsigned short* Bp1 = (unsigned short*)w; w += (size_t)256 * NF * 2;   // 64 KB
    unsigned short* Bpx = (unsigned short*)w; w += (size_t)256 * NF * 2;   // 64 KB
    unsigned short* Bp2 = (unsigned short*)w; w += (size_t)128 * 80 * 2;   // 20 KB
    int* bhist = (int*)w; w += NB * 4;
    int* bbase = (int*)w; w += NB * 4;
    int* bcurA = (int*)w; w += NB * 4;
    // overlays
    int2* stage = (int2*)h2b;        // 12.8 MB, dead until convx writes h2b
    unsigned short* t40 = xb;        // dead after conv1
    float* z40 = (float*)h1b;        // dead after convx

    // ---- zeroing ----
    hipMemsetAsync(bhist, 0, NB * 4, stream);
    hipMemsetAsync(bnbuf3, 0, (size_t)SBANK * 256 * 4, stream);
    hipMemsetAsync(bnbuf2, 0, 2 * NC * 4, stream);

    // ---- CSR build: bucket partition + merged deg/scan/fill ----
    bhist_kernel<<<PT_GRID, 256, 0, stream>>>(dstv, bhist);
    bscan_kernel<<<1, 256, 0, stream>>>(bhist, bbase, bcurA);
    part_kernel<<<PT_GRID, 256, 0, stream>>>(srcv, dstv, bcurA, stage);
    bucket_build_kernel<<<NBU, 512, 0, stream>>>((const long long*)stage, bbase, bcurA,
                                                 row_ptr, inv_cnt, csr);

    // ---- prep: x -> bf16; pack weights ----
    f2b4_kernel<<<(NN * NF / 4 + 255) / 256, 256, 0, stream>>>(x, xb, NN * NF / 4);
    pack_w_kernel<<<64, 64, 0, stream>>>(W1l, W1r, Bp1);
    pack_w_kernel<<<64, 64, 0, stream>>>(Wxl, Wxr, Bpx);
    pack_w80_kernel<<<20, 64, 0, stream>>>(W2l, W2r, Bp2);

    const int nblk_agg = (NN + 15) / 16;   // 6250

    // ---- conv1: h1 = relu([mean(x)|x] @ Bp1 + b1) -> h1b (bf16) ----
    agg_mean_bf16<<<nblk_agg, 256, 0, stream>>>(xb, csr, row_ptr, inv_cnt, aggb);
    lin_conv1_kernel<<<NTILES, 256, 0, stream>>>(aggb, xb, Bp1, b1, h1b);

    // ---- convx: h2 = [mean(h1)|h1] @ Bpx + bx -> h2b (bf16) + fused BN3 stats ----
    agg_mean_bf16<<<nblk_agg, 256, 0, stream>>>(h1b, csr, row_ptr, inv_cnt, aggb);
    lin_convx_kernel<<<NTILES, 256, 0, stream>>>(aggb, h1b, Bpx, bx, h2b, bnbuf3);

    // ---- BN3 coefficients; apply+relu fused into conv2 transform ----
    bn3_coef_kernel<<<1, 128, 0, stream>>>(bnbuf3, g3, be3, bnsc, bnsh);

    // ---- conv2 (transform-first, MFMA, BN3-apply fused on X-fragment) ----
    lin80_mfma_kernel<<<LIN80_BLKS, 256, 0, stream>>>(h2b, Bp2, b2, bnsc, bnsh, t40, z40);
    agg40_add_bf16<<<(NN + 11) / 12, 256, 0, stream>>>(t40, z40, csr, row_ptr, inv_cnt, out);

    // ---- batch_norm2 (in place on out) ----
    bn_stats2_kernel<NC><<<BN_GRID, 256, 0, stream>>>(out, bnbuf2);
    bn_apply_kernel<false><<<(NN * NC + 255) / 256, 256, 0, stream>>>(out, bnbuf2, g2, be2, NC, 1.0f / NN);
}

// Round 10
// 468.604 us; speedup vs baseline: 1.3382x; 1.3382x over previous
//
#include <hip/hip_runtime.h>
#include <hip/hip_bf16.h>

#define NN 100000
#define NE 1600000
#define NF 128
#define NC 40
#define BN_EPS 1e-5f

#define NB 256          // bucket slots (power of 2); used: (NN+511)>>9 = 196
#define NBU ((NN + 511) >> 9)
#define PT_TILE 4096    // edges per partition tile
#define PT_GRID ((NE + PT_TILE - 1) / PT_TILE)  // 391
#define SBANK 64        // stat banks (2500 stats blocks -> chains ~39)
#define NTILES (NN / 16)   // 6250 row-tiles of 16, exact
#define LIN_GRID 1250      // per nt-half; 2*1250 blocks total
#define LIN_TILES 5        // tiles per block (1250*5 = 6250)
#define LIN80_GRID 512

typedef __attribute__((ext_vector_type(8))) short short8;
typedef __attribute__((ext_vector_type(4))) float float4v;
typedef __attribute__((ext_vector_type(4))) int int4v;

__device__ __forceinline__ unsigned short f2b(float f) {
    __hip_bfloat16 h = __float2bfloat16(f);
    return *reinterpret_cast<unsigned short*>(&h);
}
__device__ __forceinline__ float b2f_hi(unsigned u) { return __uint_as_float(u & 0xffff0000u); }
__device__ __forceinline__ float b2f_lo(unsigned u) { return __uint_as_float(u << 16); }

// ---------------- CSR build: bucket-partitioned (single-writer regions) ----------------

__global__ __launch_bounds__(256) void bhist_kernel(const int* __restrict__ dst,
                                                    int* __restrict__ bhist) {
    __shared__ int lh[NB];
    int tid = threadIdx.x;
    lh[tid] = 0;
    __syncthreads();
    int base = blockIdx.x * PT_TILE;
    int cnt = min(PT_TILE, NE - base);
    const int4v* d4 = (const int4v*)(dst + base);
    int cnt4 = cnt >> 2;
    for (int i = tid; i < cnt4; i += 256) {
        int4v d = __builtin_nontemporal_load(d4 + i);
        atomicAdd(&lh[d[0] >> 9], 1);
        atomicAdd(&lh[d[1] >> 9], 1);
        atomicAdd(&lh[d[2] >> 9], 1);
        atomicAdd(&lh[d[3] >> 9], 1);
    }
    __syncthreads();
    if (lh[tid]) atomicAdd(&bhist[tid], lh[tid]);
}

__global__ __launch_bounds__(256) void bscan_kernel(const int* __restrict__ bhist,
                                                    int* __restrict__ bbase,
                                                    int* __restrict__ bcur) {
    __shared__ int lds[NB];
    int t = threadIdx.x;
    int v = bhist[t];
    lds[t] = v;
    __syncthreads();
    for (int off = 1; off < NB; off <<= 1) {
        int u = (t >= off) ? lds[t - off] : 0;
        __syncthreads();
        lds[t] += u;
        __syncthreads();
    }
    int ex = lds[t] - v;
    bbase[t] = ex;
    bcur[t] = ex;
}

__global__ __launch_bounds__(256) void part_kernel(const int* __restrict__ src,
                                                   const int* __restrict__ dst,
                                                   int* __restrict__ bcur,
                                                   int2* __restrict__ stage) {
    __shared__ int2 pairs[PT_TILE];  // 32 KB
    __shared__ int lhist[NB];
    __shared__ int gbase[NB];
    int tid = threadIdx.x;
    int base = blockIdx.x * PT_TILE;
    int cnt = min(PT_TILE, NE - base);
    int cnt4 = cnt >> 2;

    lhist[tid] = 0;
    __syncthreads();

    const int4v* d4 = (const int4v*)(dst + base);
    const int4v* s4 = (const int4v*)(src + base);
    for (int i = tid; i < cnt4; i += 256) {
        int4v d = __builtin_nontemporal_load(d4 + i);
        int4v s = __builtin_nontemporal_load(s4 + i);
#pragma unroll
        for (int j = 0; j < 4; ++j) {
            pairs[j * cnt4 + i] = make_int2(d[j], s[j]);
            atomicAdd(&lhist[d[j] >> 9], 1);
        }
    }
    __syncthreads();

    int c = lhist[tid];
    gbase[tid] = (c > 0) ? atomicAdd(&bcur[tid], c) : 0;
    lhist[tid] = 0;
    __syncthreads();

    for (int k = tid; k < cnt; k += 256) {
        int2 p = pairs[k];
        int b = p.x >> 9;
        int pos = atomicAdd(&lhist[b], 1);
        stage[gbase[b] + pos] = p;
    }
}

// Merged deg+scan+fill: one block per bucket (R7-verified).

__global__ __launch_bounds__(512) void bucket_build_kernel(const long long* __restrict__ stage,
                                                           const int* __restrict__ bbase,
                                                           const int* __restrict__ bcur,
                                                           int* __restrict__ row_ptr,
                                                           float* __restrict__ inv_cnt,
                                                           int* __restrict__ csr) {
    __shared__ int hist[512];
    __shared__ int sa[512], sb[512];  // scan ping-pong
    __shared__ int cur[512];
    int tid = threadIdx.x;
    int b = blockIdx.x;
    int s = bbase[b], e = bcur[b];

    hist[tid] = 0;
    __syncthreads();

    for (int i = s + tid; i < e; i += 512) {
        long long p = __builtin_nontemporal_load(stage + i);
        int dl = ((int)(p & 0xffffffffLL)) & 511;
        atomicAdd(&hist[dl], 1);
    }
    __syncthreads();

    sa[tid] = hist[tid];
    __syncthreads();
    int* pin = sa;
    int* pout = sb;
    for (int off = 1; off < 512; off <<= 1) {
        pout[tid] = pin[tid] + ((tid >= off) ? pin[tid - off] : 0);
        __syncthreads();
        int* t = pin; pin = pout; pout = t;
    }

    int d = hist[tid];
    int ex = pin[tid] - d;  // exclusive
    cur[tid] = ex;
    int n = b * 512 + tid;
    if (n < NN) {
        row_ptr[n] = s + ex;
        inv_cnt[n] = 1.0f / (float)(d > 0 ? d : 1);
    }
    if (b == 0 && tid == 0) row_ptr[NN] = NE;
    __syncthreads();

    for (int i = s + tid; i < e; i += 512) {
        long long p = __builtin_nontemporal_load(stage + i);
        int dl = ((int)(p & 0xffffffffLL)) & 511;
        int sv = (int)(p >> 32);
        int pos = atomicAdd(&cur[dl], 1);
        csr[s + pos] = sv;
    }
}

// ---------------- fp32 -> bf16 bulk convert ----------------

__global__ __launch_bounds__(256) void f2b4_kernel(const float* __restrict__ in,
                                                   unsigned short* __restrict__ out, int n4) {
    int i = blockIdx.x * 256 + threadIdx.x;
    if (i < n4) {
        float4 v = ((const float4*)in)[i];
        ushort4 o;
        o.x = f2b(v.x); o.y = f2b(v.y); o.z = f2b(v.z); o.w = f2b(v.w);
        ((ushort4*)out)[i] = o;
    }
}

// ---------------- pack W into MFMA fragment order ----------------

__global__ __launch_bounds__(64) void pack_w_kernel(const float* __restrict__ Wl,
                                                    const float* __restrict__ Wr,
                                                    unsigned short* __restrict__ Bp) {
    int nt = blockIdx.x & 7;
    int kk = blockIdx.x >> 3;
    int lane = threadIdx.x;
    int n = nt * 16 + (lane & 15);
    int kb = kk * 32 + (lane >> 4) * 8;
    size_t base = ((size_t)(kk * 8 + nt) * 64 + lane) * 8;
#pragma unroll
    for (int j = 0; j < 8; ++j) {
        int k = kb + j;
        float v = (k < NF) ? Wl[(size_t)n * NF + k] : Wr[(size_t)n * NF + (k - NF)];
        Bp[base + j] = f2b(v);
    }
}

__global__ __launch_bounds__(64) void pack_w80_kernel(const float* __restrict__ Wl,
                                                      const float* __restrict__ Wr,
                                                      unsigned short* __restrict__ Bp) {
    int nt = blockIdx.x % 5;
    int kk = blockIdx.x / 5;
    int lane = threadIdx.x;
    int n = nt * 16 + (lane & 15);
    int kb = kk * 32 + (lane >> 4) * 8;
    size_t base = ((size_t)(kk * 5 + nt) * 64 + lane) * 8;
#pragma unroll
    for (int j = 0; j < 8; ++j) {
        int k = kb + j;
        float v = (n < NC) ? Wl[(size_t)n * NF + k] : Wr[(size_t)(n - NC) * NF + k];
        Bp[base + j] = f2b(v);
    }
}

// ---------------- mean aggregation: quarter-wave per node ----------------

__global__ __launch_bounds__(256) void agg_mean_bf16(const unsigned short* __restrict__ X,
                                                     const int* __restrict__ csr,
                                                     const int* __restrict__ row_ptr,
                                                     const float* __restrict__ inv_cnt,
                                                     unsigned short* __restrict__ out) {
    int tid = threadIdx.x;
    int lane = tid & 63;
    int wave = tid >> 6;
    int qw = lane >> 4;
    int sl = lane & 15;
    int n = blockIdx.x * 16 + wave * 4 + qw;
    if (n >= NN) return;
    int s = row_ptr[n], e = row_ptr[n + 1];
    int foff = sl * 8;  // feature offset (8 bf16 = 16B per lane)

    float a[8];
#pragma unroll
    for (int j = 0; j < 8; ++j) a[j] = 0.f;

    int i = s;
    for (; i + 4 <= e; i += 4) {
        int s0 = csr[i], s1 = csr[i + 1], s2 = csr[i + 2], s3 = csr[i + 3];
        uint4 u0 = *(const uint4*)(X + (size_t)s0 * NF + foff);
        uint4 u1 = *(const uint4*)(X + (size_t)s1 * NF + foff);
        uint4 u2 = *(const uint4*)(X + (size_t)s2 * NF + foff);
        uint4 u3 = *(const uint4*)(X + (size_t)s3 * NF + foff);
        a[0] += b2f_lo(u0.x) + b2f_lo(u1.x) + b2f_lo(u2.x) + b2f_lo(u3.x);
        a[1] += b2f_hi(u0.x) + b2f_hi(u1.x) + b2f_hi(u2.x) + b2f_hi(u3.x);
        a[2] += b2f_lo(u0.y) + b2f_lo(u1.y) + b2f_lo(u2.y) + b2f_lo(u3.y);
        a[3] += b2f_hi(u0.y) + b2f_hi(u1.y) + b2f_hi(u2.y) + b2f_hi(u3.y);
        a[4] += b2f_lo(u0.z) + b2f_lo(u1.z) + b2f_lo(u2.z) + b2f_lo(u3.z);
        a[5] += b2f_hi(u0.z) + b2f_hi(u1.z) + b2f_hi(u2.z) + b2f_hi(u3.z);
        a[6] += b2f_lo(u0.w) + b2f_lo(u1.w) + b2f_lo(u2.w) + b2f_lo(u3.w);
        a[7] += b2f_hi(u0.w) + b2f_hi(u1.w) + b2f_hi(u2.w) + b2f_hi(u3.w);
    }
    for (; i < e; ++i) {
        uint4 u = *(const uint4*)(X + (size_t)csr[i] * NF + foff);
        a[0] += b2f_lo(u.x); a[1] += b2f_hi(u.x);
        a[2] += b2f_lo(u.y); a[3] += b2f_hi(u.y);
        a[4] += b2f_lo(u.z); a[5] += b2f_hi(u.z);
        a[6] += b2f_lo(u.w); a[7] += b2f_hi(u.w);
    }

    float ic = inv_cnt[n];
    uint4 o;
    o.x = (unsigned)f2b(a[0] * ic) | ((unsigned)f2b(a[1] * ic) << 16);
    o.y = (unsigned)f2b(a[2] * ic) | ((unsigned)f2b(a[3] * ic) << 16);
    o.z = (unsigned)f2b(a[4] * ic) | ((unsigned)f2b(a[5] * ic) << 16);
    o.w = (unsigned)f2b(a[6] * ic) | ((unsigned)f2b(a[7] * ic) << 16);
    *(uint4*)(out + (size_t)n * NF + foff) = o;
}

// ---------------- MFMA linear (128-out, K=256): all-LDS operand routing ----------------
// Theory (R5/R9 evidence): hipcc serializes global loads consumed by MFMA
// (per-use vmcnt drain), but clusters loads consumed by VALU/ds_write
// (agg_mean reaches 3.6 TB/s). So NO global load may feed an MFMA:
//   global -> reg -> ds_write (clusters) -> barrier -> ds_read -> MFMA
// nt-split: block half h owns nt h*4..h*4+3 (B half-panel 32 KB in LDS),
// wave = one nt. A/X tiles double-buffered (2x8 KB), XOR-swizzled
// (slot = row*16 + (col16 ^ (row&7))) so the 16-rows-same-col ds_read_b128
// is 2-way/free. One barrier per tile. LDS 50 KB -> 3 blocks/CU.

template <bool RELU, bool STATS>
__device__ __forceinline__ void lin_body(const unsigned short* __restrict__ Ab,
                                         const unsigned short* __restrict__ Xb,
                                         const unsigned short* __restrict__ Bp,
                                         const float* __restrict__ bias,
                                         unsigned short* __restrict__ outb,
                                         float* __restrict__ sums,
                                         uint4* Bsv, uint4* Tls, float* ls) {
    int tid = threadIdx.x;
    int wave = tid >> 6;
    int lane = tid & 63;
    int quad = lane >> 4;
    int sl = lane & 15;
    int h = blockIdx.x & 1;        // nt half
    int b0 = blockIdx.x >> 1;      // 0..1249
    int nt = h * 4 + wave;

    // ---- stage B half-panel (32 KB): loads feed ds_writes -> cluster ----
    const uint4* Bg = (const uint4*)Bp;
#pragma unroll
    for (int j = 0; j < 8; ++j) {
        int s = j * 256 + tid;
        int l = s >> 6, ln = s & 63;
        int gf = (l >> 2) * 8 + h * 4 + (l & 3);   // lds frag l = kk*4 + w
        Bsv[s] = Bg[gf * 64 + ln];
    }
    if (STATS) ls[tid] = 0.f;

    // ---- prologue: stage tile 0 into buf0 (swizzled) ----
    int row0 = tid >> 4, cs = tid & 15;
    int wslot = row0 * 16 + (cs ^ (row0 & 7));
    {
        int rr = b0 * 16 + row0;
        uint4 ra = *(const uint4*)(Ab + (size_t)rr * NF + cs * 8);
        uint4 rx = *(const uint4*)(Xb + (size_t)rr * NF + cs * 8);
        Tls[wslot] = ra;
        Tls[256 + wslot] = rx;
    }
    __syncthreads();

    float4 bias4 = *(const float4*)(bias + nt * 16 + quad * 4);
    float sv[4], qv[4];
#pragma unroll
    for (int r = 0; r < 4; ++r) { sv[r] = 0.f; qv[r] = 0.f; }

#pragma unroll
    for (int i = 0; i < LIN_TILES; ++i) {
        const int cur = i & 1;
        const int nxt = cur ^ 1;
        int t = b0 + i * LIN_GRID;

        // issue next tile's loads EARLY (consumers are ds_writes below)
        uint4 ra, rx;
        if (i + 1 < LIN_TILES) {
            int rr1 = (b0 + (i + 1) * LIN_GRID) * 16 + row0;
            ra = *(const uint4*)(Ab + (size_t)rr1 * NF + cs * 8);
            rx = *(const uint4*)(Xb + (size_t)rr1 * NF + cs * 8);
        }

        // compute tile t from buf cur: ds_read -> MFMA only
        float4v acc = (float4v){0.f, 0.f, 0.f, 0.f};
#pragma unroll
        for (int kk = 0; kk < 8; ++kk) {
            int kcol = (kk & 3) * 4 + quad;
            int xslot = cur * 512 + ((kk < 4) ? 0 : 256) + sl * 16 + (kcol ^ (sl & 7));
            short8 xf = *(const short8*)(Tls + xslot);
            short8 bf = *(const short8*)(Bsv + (kk * 4 + wave) * 64 + lane);
            acc = __builtin_amdgcn_mfma_f32_16x16x32_bf16(bf, xf, acc, 0, 0, 0);
        }

        int rr = t * 16 + sl;
        int c0 = nt * 16 + quad * 4;
        float v0 = acc[0] + bias4.x;
        float v1 = acc[1] + bias4.y;
        float v2 = acc[2] + bias4.z;
        float v3 = acc[3] + bias4.w;
        if (RELU) {
            v0 = fmaxf(v0, 0.f); v1 = fmaxf(v1, 0.f);
            v2 = fmaxf(v2, 0.f); v3 = fmaxf(v3, 0.f);
        }
        if (STATS) {
            sv[0] += v0; qv[0] += v0 * v0;
            sv[1] += v1; qv[1] += v1 * v1;
            sv[2] += v2; qv[2] += v2 * v2;
            sv[3] += v3; qv[3] += v3 * v3;
        }
        ushort4 o;
        o.x = f2b(v0); o.y = f2b(v1); o.z = f2b(v2); o.w = f2b(v3);
        *(ushort4*)(outb + (size_t)rr * NF + c0) = o;

        // write next tile into the other buffer (no conflict with cur)
        if (i + 1 < LIN_TILES) {
            Tls[nxt * 512 + wslot] = ra;
            Tls[nxt * 512 + 256 + wslot] = rx;
        }
        __syncthreads();
    }

    if (STATS) {
        int c0 = nt * 16 + quad * 4;
#pragma unroll
        for (int r = 0; r < 4; ++r) {
            atomicAdd(&ls[c0 + r], sv[r]);
            atomicAdd(&ls[128 + c0 + r], qv[r]);
        }
        __syncthreads();
        // only this block's nt-half of ls is nonzero
        if (((tid & 127) >> 6) == h)
            atomicAdd(&sums[(blockIdx.x & (SBANK - 1)) * 256 + tid], ls[tid]);
    }
}

__global__ __launch_bounds__(256, 3) void lin_conv1_kernel(const unsigned short* __restrict__ Ab,
                                                           const unsigned short* __restrict__ Xb,
                                                           const unsigned short* __restrict__ Bp,
                                                           const float* __restrict__ bias,
                                                           unsigned short* __restrict__ outb) {
    __shared__ uint4 Bsv[2048];   // 32 KB
    __shared__ uint4 Tls[1024];   // 16 KB (2 bufs x [A|X] x 256 slots)
    lin_body<true, false>(Ab, Xb, Bp, bias, outb, nullptr, Bsv, Tls, nullptr);
}

__global__ __launch_bounds__(256, 3) void lin_convx_kernel(const unsigned short* __restrict__ Ab,
                                                           const unsigned short* __restrict__ Xb,
                                                           const unsigned short* __restrict__ Bp,
                                                           const float* __restrict__ bias,
                                                           unsigned short* __restrict__ outb,
                                                           float* __restrict__ sums) {
    __shared__ uint4 Bsv[2048];
    __shared__ uint4 Tls[1024];
    __shared__ float ls[256];
    lin_body<false, true>(Ab, Xb, Bp, bias, outb, sums, Bsv, Tls, ls);
}

// ---------------- BN3 coefficients: fold banked sums, scale/shift per column ----------------

__global__ __launch_bounds__(128) void bn3_coef_kernel(const float* __restrict__ sums,
                                                       const float* __restrict__ g,
                                                       const float* __restrict__ be,
                                                       float* __restrict__ sc,
                                                       float* __restrict__ sh) {
    int c = threadIdx.x;
    float sv = 0.f, qv = 0.f;
    for (int b = 0; b < SBANK; ++b) {
        sv += sums[b * 256 + c];
        qv += sums[b * 256 + 128 + c];
    }
    float invN = 1.0f / (float)NN;
    float mu = sv * invN;
    float var = qv * invN - mu * mu;
    float s = rsqrtf(var + BN_EPS) * g[c];
    sc[c] = s;
    sh[c] = be[c] - mu * s;
}

// ---------------- MFMA linear conv2 (80-out, K=128), per-wave tile stream (R7 form) ----------------

__global__ __launch_bounds__(256, 2) void lin80_mfma_kernel(const unsigned short* __restrict__ Xb,
                                                            const unsigned short* __restrict__ Bp,
                                                            const float* __restrict__ b2,
                                                            const float* __restrict__ bnsc,
                                                            const float* __restrict__ bnsh,
                                                            unsigned short* __restrict__ t40,
                                                            float* __restrict__ z40) {
    int tid = threadIdx.x;
    int wave = tid >> 6;
    int lane = tid & 63;
    int quad = lane >> 4;
    int sl = lane & 15;
    const short8* Bv = (const short8*)Bp;

    short8 bfr[4][5];
#pragma unroll
    for (int kk = 0; kk < 4; ++kk)
#pragma unroll
        for (int nt = 0; nt < 5; ++nt)
            bfr[kk][nt] = Bv[(kk * 5 + nt) * 64 + lane];

    float4 sc0[4], sc1[4], sh0[4], sh1[4];
#pragma unroll
    for (int kk = 0; kk < 4; ++kk) {
        int kb = kk * 32 + quad * 8;
        sc0[kk] = *(const float4*)(bnsc + kb);
        sc1[kk] = *(const float4*)(bnsc + kb + 4);
        sh0[kk] = *(const float4*)(bnsh + kb);
        sh1[kk] = *(const float4*)(bnsh + kb + 4);
    }

    int gw = blockIdx.x * 4 + wave;
    for (int t = gw; t < NTILES; t += LIN80_GRID * 4) {
        int rr = t * 16 + sl;
        const unsigned short* xrow = Xb + (size_t)rr * NF;

        float4v acc[5];
#pragma unroll
        for (int nt = 0; nt < 5; ++nt) acc[nt] = (float4v){0.f, 0.f, 0.f, 0.f};

#pragma unroll
        for (int kk = 0; kk < 4; ++kk) {
            uint4 u = *(const uint4*)(xrow + kk * 32 + quad * 8);
            short8 xf;
            xf[0] = (short)f2b(fmaxf(b2f_lo(u.x) * sc0[kk].x + sh0[kk].x, 0.f));
            xf[1] = (short)f2b(fmaxf(b2f_hi(u.x) * sc0[kk].y + sh0[kk].y, 0.f));
            xf[2] = (short)f2b(fmaxf(b2f_lo(u.y) * sc0[kk].z + sh0[kk].z, 0.f));
            xf[3] = (short)f2b(fmaxf(b2f_hi(u.y) * sc0[kk].w + sh0[kk].w, 0.f));
            xf[4] = (short)f2b(fmaxf(b2f_lo(u.z) * sc1[kk].x + sh1[kk].x, 0.f));
            xf[5] = (short)f2b(fmaxf(b2f_hi(u.z) * sc1[kk].y + sh1[kk].y, 0.f));
            xf[6] = (short)f2b(fmaxf(b2f_lo(u.w) * sc1[kk].z + sh1[kk].z, 0.f));
            xf[7] = (short)f2b(fmaxf(b2f_hi(u.w) * sc1[kk].w + sh1[kk].w, 0.f));
#pragma unroll
            for (int nt = 0; nt < 5; ++nt)
                acc[nt] = __builtin_amdgcn_mfma_f32_16x16x32_bf16(bfr[kk][nt], xf, acc[nt], 0, 0, 0);
        }

#pragma unroll
        for (int nt = 0; nt < 5; ++nt) {
            int c0 = nt * 16 + quad * 4;
            if (c0 < NC) {
                ushort4 o;
                o.x = f2b(acc[nt][0]); o.y = f2b(acc[nt][1]);
                o.z = f2b(acc[nt][2]); o.w = f2b(acc[nt][3]);
                *(ushort4*)(t40 + (size_t)rr * NC + c0) = o;
            } else {
                float4 bz = *(const float4*)(b2 + c0 - NC);
                float4 o;
                o.x = acc[nt][0] + bz.x; o.y = acc[nt][1] + bz.y;
                o.z = acc[nt][2] + bz.z; o.w = acc[nt][3] + bz.w;
                *(float4*)(z40 + (size_t)rr * NC + (c0 - NC)) = o;
            }
        }
    }
}

// ---------------- conv2 aggregation: 3 nodes/wave (R7 form) ----------------

__global__ __launch_bounds__(256) void agg40_add_bf16(const unsigned short* __restrict__ T,
                                                      const float* __restrict__ Z,
                                                      const int* __restrict__ csr,
                                                      const int* __restrict__ row_ptr,
                                                      const float* __restrict__ inv_cnt,
                                                      float* __restrict__ out) {
    int tid = threadIdx.x;
    int lane = tid & 63;
    int wave = tid >> 6;
    if (lane >= 60) return;
    int sub = lane / 20;
    int sl = lane % 20;
    int n = blockIdx.x * 12 + wave * 3 + sub;
    if (n >= NN) return;
    int s = row_ptr[n], e = row_ptr[n + 1];
    const unsigned short* Tf = T + sl * 2;
    float a0 = 0.f, a1 = 0.f;
    int i = s;
    for (; i + 4 <= e; i += 4) {
        int s0 = csr[i], s1 = csr[i + 1], s2 = csr[i + 2], s3 = csr[i + 3];
        unsigned u0 = *(const unsigned*)(Tf + (size_t)s0 * NC);
        unsigned u1 = *(const unsigned*)(Tf + (size_t)s1 * NC);
        unsigned u2 = *(const unsigned*)(Tf + (size_t)s2 * NC);
        unsigned u3 = *(const unsigned*)(Tf + (size_t)s3 * NC);
        a0 += b2f_lo(u0) + b2f_lo(u1) + b2f_lo(u2) + b2f_lo(u3);
        a1 += b2f_hi(u0) + b2f_hi(u1) + b2f_hi(u2) + b2f_hi(u3);
    }
    for (; i < e; ++i) {
        unsigned u = *(const unsigned*)(Tf + (size_t)csr[i] * NC);
        a0 += b2f_lo(u);
        a1 += b2f_hi(u);
    }
    float ic = inv_cnt[n];
    const float2 zv = *(const float2*)(Z + (size_t)n * NC + sl * 2);
    float2 o;
    o.x = a0 * ic + zv.x;
    o.y = a1 * ic + zv.y;
    *(float2*)(out + (size_t)n * NC + sl * 2) = o;
}

// ---------------- batch norm (final, NC) ----------------
#define BN_GRID 640  // 640*256 divisible by 10 (F=40)

template <int F>
__global__ __launch_bounds__(256) void bn_stats2_kernel(const float* __restrict__ X,
                                                        float* __restrict__ sums) {
    __shared__ float ls[2 * F];
    int tid = threadIdx.x;
    for (int i = tid; i < 2 * F; i += 256) ls[i] = 0.f;
    __syncthreads();

    const int total4 = NN * F / 4;
    const int stride = BN_GRID * 256;
    int i0 = blockIdx.x * 256 + tid;
    int c0 = (i0 * 4) % F;
    float s0 = 0.f, s1 = 0.f, s2 = 0.f, s3 = 0.f;
    float q0 = 0.f, q1 = 0.f, q2 = 0.f, q3 = 0.f;
    for (int i = i0; i < total4; i += stride) {
        float4 v = ((const float4*)X)[i];
        s0 += v.x; q0 += v.x * v.x;
        s1 += v.y; q1 += v.y * v.y;
        s2 += v.z; q2 += v.z * v.z;
        s3 += v.w; q3 += v.w * v.w;
    }
    atomicAdd(&ls[c0 + 0], s0); atomicAdd(&ls[F + c0 + 0], q0);
    atomicAdd(&ls[c0 + 1], s1); atomicAdd(&ls[F + c0 + 1], q1);
    atomicAdd(&ls[c0 + 2], s2); atomicAdd(&ls[F + c0 + 2], q2);
    atomicAdd(&ls[c0 + 3], s3); atomicAdd(&ls[F + c0 + 3], q3);
    __syncthreads();
    for (int i = tid; i < 2 * F; i += 256) atomicAdd(&sums[i], ls[i]);
}

template <bool RELU>
__global__ __launch_bounds__(256) void bn_apply_kernel(float* __restrict__ X,
                                                       const float* __restrict__ sums,
                                                       const float* __restrict__ g,
                                                       const float* __restrict__ be,
                                                       int F, float invN) {
    size_t idx = (size_t)blockIdx.x * blockDim.x + threadIdx.x;
    size_t total = (size_t)NN * F;
    if (idx >= total) return;
    int t = (int)(idx % F);
    float mu = sums[t] * invN;
    float var = sums[F + t] * invN - mu * mu;
    float scale = rsqrtf(var + BN_EPS) * g[t];
    float v = (X[idx] - mu) * scale + be[t];
    if (RELU) v = fmaxf(v, 0.f);
    X[idx] = v;
}

// ---------------- launch ----------------

extern "C" void kernel_launch(void* const* d_in, const int* in_sizes, int n_in,
                              void* d_out, int out_size, void* d_ws, size_t ws_size,
                              hipStream_t stream) {
    const float* x   = (const float*)d_in[0];
    const int*   ei  = (const int*)d_in[1];
    const int*   srcv = ei;
    const int*   dstv = ei + NE;
    const float* W1l = (const float*)d_in[2];
    const float* b1  = (const float*)d_in[3];
    const float* W1r = (const float*)d_in[4];
    const float* Wxl = (const float*)d_in[5];
    const float* bx  = (const float*)d_in[6];
    const float* Wxr = (const float*)d_in[7];
    const float* W2l = (const float*)d_in[8];
    const float* b2  = (const float*)d_in[9];
    const float* W2r = (const float*)d_in[10];
    const float* g3  = (const float*)d_in[11];
    const float* be3 = (const float*)d_in[12];
    const float* g2  = (const float*)d_in[13];
    const float* be2 = (const float*)d_in[14];
    float* out = (float*)d_out;

    // workspace carve (16B aligned)
    char* w = (char*)d_ws;
    unsigned short* xb   = (unsigned short*)w; w += (size_t)NN * NF * 2;   // 25.6 MB
    unsigned short* h1b  = (unsigned short*)w; w += (size_t)NN * NF * 2;   // 25.6 MB
    unsigned short* aggb = (unsigned short*)w; w += (size_t)NN * NF * 2;   // 25.6 MB
    unsigned short* h2b  = (unsigned short*)w; w += (size_t)NN * NF * 2;   // 25.6 MB
    int* csr     = (int*)w; w += (size_t)NE * 4;                           // 6.4 MB
    int* row_ptr = (int*)w; w += (size_t)(NN + 4) * 4;
    float* inv_cnt = (float*)w; w += (size_t)NN * 4;
    float* bnbuf3  = (float*)w; w += (size_t)SBANK * 256 * 4;              // 64 KB banked
    float* bnbuf2  = (float*)w; w += 2 * NC * 4;
    float* bnsc    = (float*)w; w += NF * 4;
    float* bnsh    = (float*)w; w += NF * 4;
    unsigned short* Bp1 = (unsigned short*)w; w += (size_t)256 * NF * 2;   // 64 KB
    unsigned short* Bpx = (unsigned short*)w; w += (size_t)256 * NF * 2;   // 64 KB
    unsigned short* Bp2 = (unsigned short*)w; w += (size_t)128 * 80 * 2;   // 20 KB
    int* bhist = (int*)w; w += NB * 4;
    int* bbase = (int*)w; w += NB * 4;
    int* bcurA = (int*)w; w += NB * 4;
    // overlays
    int2* stage = (int2*)h2b;        // 12.8 MB, dead until convx writes h2b
    unsigned short* t40 = xb;        // dead after conv1
    float* z40 = (float*)h1b;        // dead after convx

    // ---- zeroing ----
    hipMemsetAsync(bhist, 0, NB * 4, stream);
    hipMemsetAsync(bnbuf3, 0, (size_t)SBANK * 256 * 4, stream);
    hipMemsetAsync(bnbuf2, 0, 2 * NC * 4, stream);

    // ---- CSR build: bucket partition + merged deg/scan/fill ----
    bhist_kernel<<<PT_GRID, 256, 0, stream>>>(dstv, bhist);
    bscan_kernel<<<1, 256, 0, stream>>>(bhist, bbase, bcurA);
    part_kernel<<<PT_GRID, 256, 0, stream>>>(srcv, dstv, bcurA, stage);
    bucket_build_kernel<<<NBU, 512, 0, stream>>>((const long long*)stage, bbase, bcurA,
                                                 row_ptr, inv_cnt, csr);

    // ---- prep: x -> bf16; pack weights ----
    f2b4_kernel<<<(NN * NF / 4 + 255) / 256, 256, 0, stream>>>(x, xb, NN * NF / 4);
    pack_w_kernel<<<64, 64, 0, stream>>>(W1l, W1r, Bp1);
    pack_w_kernel<<<64, 64, 0, stream>>>(Wxl, Wxr, Bpx);
    pack_w80_kernel<<<20, 64, 0, stream>>>(W2l, W2r, Bp2);

    const int nblk_agg = (NN + 15) / 16;   // 6250

    // ---- conv1: h1 = relu([mean(x)|x] @ Bp1 + b1) -> h1b (bf16) ----
    agg_mean_bf16<<<nblk_agg, 256, 0, stream>>>(xb, csr, row_ptr, inv_cnt, aggb);
    lin_conv1_kernel<<<2 * LIN_GRID, 256, 0, stream>>>(aggb, xb, Bp1, b1, h1b);

    // ---- convx: h2 = [mean(h1)|h1] @ Bpx + bx -> h2b (bf16) + fused BN3 stats ----
    agg_mean_bf16<<<nblk_agg, 256, 0, stream>>>(h1b, csr, row_ptr, inv_cnt, aggb);
    lin_convx_kernel<<<2 * LIN_GRID, 256, 0, stream>>>(aggb, h1b, Bpx, bx, h2b, bnbuf3);

    // ---- BN3 coefficients; apply+relu fused into conv2 transform ----
    bn3_coef_kernel<<<1, 128, 0, stream>>>(bnbuf3, g3, be3, bnsc, bnsh);

    // ---- conv2 (transform-first, MFMA, BN3-apply fused on X-fragment) ----
    lin80_mfma_kernel<<<LIN80_GRID, 256, 0, stream>>>(h2b, Bp2, b2, bnsc, bnsh, t40, z40);
    agg40_add_bf16<<<(NN + 11) / 12, 256, 0, stream>>>(t40, z40, csr, row_ptr, inv_cnt, out);

    // ---- batch_norm2 (in place on out) ----
    bn_stats2_kernel<NC><<<BN_GRID, 256, 0, stream>>>(out, bnbuf2);
    bn_apply_kernel<false><<<(NN * NC + 255) / 256, 256, 0, stream>>>(out, bnbuf2, g2, be2, NC, 1.0f / NN);
}